// Round 2
// baseline (523.004 us; speedup 1.0000x reference)
//
#include <hip/hip_runtime.h>

// MeshTorchLayer: 512-layer sequential complex pairwise-mixing chain.
// U=512 modes, L=512 layers, B=256 batch. mask==1; perms hardcoded:
// after layer l (0-based): l even -> carry[u]=y[u-1]; l odd -> carry[u]=y[u+1];
// after last layer (511): identity.

#define UU 512
#define LL 512
#define BB 256
#define KK 256   // U/2

// ---------------------------------------------------------------------------
// Kernel 1: precompute coef[l][u] = {diag.re, diag.im, off.re, off.im}
//   ip(u) = e^{i*theta[l][u/2]} if u even else 1;  ep(u) likewise with phi
//   sd = epp[u]*ip(u) - enn[u]*ip(u+1) - enn[u-1]*ip(u-1) + epp[u-1]*ip(u)
//   diag = 0.5 * ep(u) (x) sd
//   so = epn[u]*ip(u) + enp[u]*ip(u+1) + enp[u-1]*ip(u-1) + epn[u-1]*ip(u)
//   off  = 0.5 * ep(u-1) (x) (i*so)
// ---------------------------------------------------------------------------
__global__ __launch_bounds__(256) void mesh_precompute(
    const float* __restrict__ theta, const float* __restrict__ phi,
    const float* __restrict__ enn,   const float* __restrict__ enp,
    const float* __restrict__ epn,   const float* __restrict__ epp,
    float4* __restrict__ coef)
{
    const int l  = blockIdx.x * 256 + threadIdx.x;
    const int u  = blockIdx.y;
    const int um = (u + UU - 1) & (UU - 1);

    const float epp_u  = epp[u * LL + l],  epp_um = epp[um * LL + l];
    const float enn_u  = enn[u * LL + l],  enn_um = enn[um * LL + l];
    const float enp_u  = enp[u * LL + l],  enp_um = enp[um * LL + l];
    const float epn_u  = epn[u * LL + l],  epn_um = epn[um * LL + l];

    float ipu_r, ipu_i, ipp_r, ipp_i, ipm_r, ipm_i;
    float epu_r, epu_i, epm_r, epm_i;

    if ((u & 1) == 0) {
        const int k = u >> 1;
        float th = theta[l * KK + k];
        __sincosf(th, &ipu_i, &ipu_r);
        ipp_r = 1.f; ipp_i = 0.f;      // u+1 odd -> angle 0
        ipm_r = 1.f; ipm_i = 0.f;      // u-1 odd -> angle 0
        float ph = phi[l * KK + k];
        __sincosf(ph, &epu_i, &epu_r);
        epm_r = 1.f; epm_i = 0.f;
    } else {
        ipu_r = 1.f; ipu_i = 0.f;
        float thp = theta[l * KK + (((u + 1) >> 1) & (KK - 1))]; // mode u+1 (wraps 511->0)
        __sincosf(thp, &ipp_i, &ipp_r);
        float thm = theta[l * KK + (u >> 1)];                    // mode u-1
        __sincosf(thm, &ipm_i, &ipm_r);
        epu_r = 1.f; epu_i = 0.f;
        float phm = phi[l * KK + (u >> 1)];
        __sincosf(phm, &epm_i, &epm_r);
    }

    const float sd_r = epp_u * ipu_r - enn_u * ipp_r - enn_um * ipm_r + epp_um * ipu_r;
    const float sd_i = epp_u * ipu_i - enn_u * ipp_i - enn_um * ipm_i + epp_um * ipu_i;
    const float d_r = 0.5f * (epu_r * sd_r - epu_i * sd_i);
    const float d_i = 0.5f * (epu_r * sd_i + epu_i * sd_r);

    const float so_r = epn_u * ipu_r + enp_u * ipp_r + enp_um * ipm_r + epn_um * ipu_r;
    const float so_i = epn_u * ipu_i + enp_u * ipp_i + enp_um * ipm_i + epn_um * ipu_i;
    const float soi_r = -so_i, soi_i = so_r;               // i * so
    const float o_r = 0.5f * (epm_r * soi_r - epm_i * soi_i);
    const float o_i = 0.5f * (epm_r * soi_i + epm_i * soi_r);

    coef[l * UU + u] = make_float4(d_r, d_i, o_r, o_i);
}

// ---------------------------------------------------------------------------
// Kernel 2: chain. One WAVE owns one batch; lane ln owns 4 contiguous pairs
// = modes 8ln..8ln+7, carried in registers across all 512 layers.
// Pair mix (pair p, global modes 2P,2P+1):
//   y0 = c0 (x) d[2P]   + c1 (x) o[2P+1]
//   y1 = c1 (x) d[2P+1] + c0 (x) o[2P]
// Roll: even layer carry[u]=y[u-1]: c0'[p]=y1[p-1] (p=0 from lane-1, circular),
//       c1'[p]=y0[p]. Odd layer carry[u]=y[u+1]: c0'[p]=y1[p],
//       c1'[p]=y0[p+1] (p=3 from lane+1, circular). Last layer: identity.
// ONE float2 __shfl per layer, zero barriers. WG=256=4 waves=4 batches.
// ---------------------------------------------------------------------------
#define PAIR_MIX(K)                                                         \
    _Pragma("unroll")                                                       \
    for (int p = 0; p < 4; ++p) {                                           \
        const float4 ke = K[2*p], ko = K[2*p+1];                            \
        y0r[p] = c0r[p]*ke.x - c0i[p]*ke.y + c1r[p]*ko.z - c1i[p]*ko.w;     \
        y0i[p] = c0r[p]*ke.y + c0i[p]*ke.x + c1r[p]*ko.w + c1i[p]*ko.z;     \
        y1r[p] = c1r[p]*ko.x - c1i[p]*ko.y + c0r[p]*ke.z - c0i[p]*ke.w;     \
        y1i[p] = c1r[p]*ko.y + c1i[p]*ko.x + c0r[p]*ke.w + c0i[p]*ke.z;     \
    }

__global__ __launch_bounds__(256) void mesh_chain(
    const float* __restrict__ x, const float* __restrict__ gamma,
    const float4* __restrict__ coef, float* __restrict__ out)
{
    const int lane = threadIdx.x & 63;
    const int wv   = threadIdx.x >> 6;
    const int b    = blockIdx.x * 4 + wv;
    const int m0   = lane << 3;               // first of this lane's 8 modes

    // ---- init: c = x * e^{i gamma} ----
    const float4 xr0 = *(const float4*)(x + b * UU + m0);
    const float4 xr1 = *(const float4*)(x + b * UU + m0 + 4);
    const float4 xi0 = *(const float4*)(x + BB * UU + b * UU + m0);
    const float4 xi1 = *(const float4*)(x + BB * UU + b * UU + m0 + 4);
    const float xr[8] = {xr0.x, xr0.y, xr0.z, xr0.w, xr1.x, xr1.y, xr1.z, xr1.w};
    const float xi[8] = {xi0.x, xi0.y, xi0.z, xi0.w, xi1.x, xi1.y, xi1.z, xi1.w};

    float c0r[4], c0i[4], c1r[4], c1i[4];
    #pragma unroll
    for (int p = 0; p < 4; ++p) {
        float s0, cg0, s1, cg1;
        __sincosf(gamma[m0 + 2*p],     &s0, &cg0);
        __sincosf(gamma[m0 + 2*p + 1], &s1, &cg1);
        c0r[p] = xr[2*p] * cg0 - xi[2*p] * s0;
        c0i[p] = xr[2*p] * s0  + xi[2*p] * cg0;
        c1r[p] = xr[2*p+1] * cg1 - xi[2*p+1] * s1;
        c1i[p] = xr[2*p+1] * s1  + xi[2*p+1] * cg1;
    }

    const float4* cp = coef + m0;             // this lane's 8 coef slots, row stride UU
    float4 k[8], n[8];
    #pragma unroll
    for (int q = 0; q < 8; ++q) k[q] = cp[q];
    cp += UU;

    const int laneM1 = (lane + 63) & 63;
    const int laneP1 = (lane + 1) & 63;

    for (int it = 0; it < 256; ++it) {
        // prefetch odd-layer coefs
        #pragma unroll
        for (int q = 0; q < 8; ++q) n[q] = cp[q];
        cp += UU;

        float y0r[4], y0i[4], y1r[4], y1i[4];

        // ---- even layer 2*it : carry[u] = y[u-1] ----
        PAIR_MIX(k)
        {
            const float br = __shfl(y1r[3], laneM1, 64);
            const float bi = __shfl(y1i[3], laneM1, 64);
            #pragma unroll
            for (int p = 3; p > 0; --p) { c0r[p] = y1r[p-1]; c0i[p] = y1i[p-1]; }
            c0r[0] = br; c0i[0] = bi;
            #pragma unroll
            for (int p = 0; p < 4; ++p) { c1r[p] = y0r[p]; c1i[p] = y0i[p]; }
        }

        const bool last = (it == 255);
        if (!last) {   // prefetch next even-layer coefs
            #pragma unroll
            for (int q = 0; q < 8; ++q) k[q] = cp[q];
            cp += UU;
        }

        // ---- odd layer 2*it+1 ----
        PAIR_MIX(n)
        if (!last) {   // carry[u] = y[u+1]
            const float br = __shfl(y0r[0], laneP1, 64);
            const float bi = __shfl(y0i[0], laneP1, 64);
            #pragma unroll
            for (int p = 0; p < 3; ++p) { c0r[p] = y1r[p]; c0i[p] = y1i[p];
                                          c1r[p] = y0r[p+1]; c1i[p] = y0i[p+1]; }
            c0r[3] = y1r[3]; c0i[3] = y1i[3];
            c1r[3] = br;     c1i[3] = bi;
        } else {       // layer 511: identity perm
            #pragma unroll
            for (int p = 0; p < 4; ++p) { c0r[p] = y0r[p]; c0i[p] = y0i[p];
                                          c1r[p] = y1r[p]; c1i[p] = y1i[p]; }
        }
    }

    // ---- store out[0][b][u] (re), out[1][b][u] (im) ----
    *(float4*)(out + b * UU + m0)               = make_float4(c0r[0], c1r[0], c0r[1], c1r[1]);
    *(float4*)(out + b * UU + m0 + 4)           = make_float4(c0r[2], c1r[2], c0r[3], c1r[3]);
    *(float4*)(out + BB * UU + b * UU + m0)     = make_float4(c0i[0], c1i[0], c0i[1], c1i[1]);
    *(float4*)(out + BB * UU + b * UU + m0 + 4) = make_float4(c0i[2], c1i[2], c0i[3], c1i[3]);
}

extern "C" void kernel_launch(void* const* d_in, const int* in_sizes, int n_in,
                              void* d_out, int out_size, void* d_ws, size_t ws_size,
                              hipStream_t stream) {
    (void)in_sizes; (void)n_in; (void)out_size; (void)ws_size;
    const float* x     = (const float*)d_in[0];
    const float* theta = (const float*)d_in[1];
    const float* phi   = (const float*)d_in[2];
    const float* gamma = (const float*)d_in[3];
    // d_in[4] = mask (all ones, folded out)
    const float* enn   = (const float*)d_in[5];
    const float* enp   = (const float*)d_in[6];
    const float* epn   = (const float*)d_in[7];
    const float* epp   = (const float*)d_in[8];
    // d_in[9] = perms, d_in[10] = pairwise_perm (fixed patterns, hardcoded)

    float4* coef = (float4*)d_ws;              // L*U*16B = 4 MB scratch
    float*  out  = (float*)d_out;

    dim3 pgrid(2, UU);
    mesh_precompute<<<pgrid, 256, 0, stream>>>(theta, phi, enn, enp, epn, epp, coef);
    mesh_chain<<<BB / 4, 256, 0, stream>>>(x, gamma, coef, out);
}

// Round 3
// 284.416 us; speedup vs baseline: 1.8389x; 1.8389x over previous
//
#include <hip/hip_runtime.h>

// MeshTorchLayer: 512-layer sequential complex pairwise-mixing chain.
// U=512 modes, L=512 layers, B=256 batch. mask==1; perms hardcoded:
// after layer l (0-based): l even -> carry[u]=y[u-1]; l odd -> carry[u]=y[u+1];
// after last layer (511): identity.
//
// R3: chain is latency-bound (R2: 2100 cyc/layer, VALUBusy 4%). Fix:
//  - per-wave private LDS ring (6 layers x 8KB) filled by global_load_lds,
//    throttled with manual s_waitcnt vmcnt(40); zero barriers.
//  - coef stored per-layer TRANSPOSED: slot(u) = (u&7)*64 + (u>>3), so the
//    wave's ds_read q hits lane-dense (16B-stride) LDS -> conflict-free and
//    compile-time register indices.
//  - WG=64 (1 wave = 1 batch), grid=256 -> 1 wave/CU on all 256 CUs.

#define UU 512
#define LL 512
#define BB 256
#define KK 256   // U/2
#define RSLOTS 6 // LDS ring depth in layers (48 KB); max in-flight 48 loads <= 63

// s_waitcnt vmcnt(40), expcnt/lgkmcnt = no-wait:
// imm = (40&0xF) | ((40>>4)<<14) | (7<<4) | (15<<8) = 0x8F78
#define WAITVM40() __builtin_amdgcn_s_waitcnt(0x8F78)

#define STAGE(g, s)                                                          \
    _Pragma("unroll")                                                        \
    for (int j = 0; j < 8; ++j)                                              \
        __builtin_amdgcn_global_load_lds(                                    \
            (const __attribute__((address_space(1))) void*)(coef + (g) * UU + j * 64 + lane), \
            (__attribute__((address_space(3))) void*)&ring[(s) * UU + j * 64], \
            16, 0, 0);

// ---------------------------------------------------------------------------
// Kernel 1: precompute coef[l][slot(u)] = {diag.re, diag.im, off.re, off.im}
// threads over u (theta/phi coalesced), block = layer l.
// ---------------------------------------------------------------------------
__global__ __launch_bounds__(512) void mesh_precompute(
    const float* __restrict__ theta, const float* __restrict__ phi,
    const float* __restrict__ enn,   const float* __restrict__ enp,
    const float* __restrict__ epn,   const float* __restrict__ epp,
    float4* __restrict__ coef)
{
    const int u  = threadIdx.x;
    const int l  = blockIdx.x;
    const int um = (u + UU - 1) & (UU - 1);

    const float epp_u  = epp[u * LL + l],  epp_um = epp[um * LL + l];
    const float enn_u  = enn[u * LL + l],  enn_um = enn[um * LL + l];
    const float enp_u  = enp[u * LL + l],  enp_um = enp[um * LL + l];
    const float epn_u  = epn[u * LL + l],  epn_um = epn[um * LL + l];

    float ipu_r, ipu_i, ipp_r, ipp_i, ipm_r, ipm_i;
    float epu_r, epu_i, epm_r, epm_i;

    if ((u & 1) == 0) {
        const int k = u >> 1;
        float th = theta[l * KK + k];
        __sincosf(th, &ipu_i, &ipu_r);
        ipp_r = 1.f; ipp_i = 0.f;      // u+1 odd -> angle 0
        ipm_r = 1.f; ipm_i = 0.f;      // u-1 odd -> angle 0
        float ph = phi[l * KK + k];
        __sincosf(ph, &epu_i, &epu_r);
        epm_r = 1.f; epm_i = 0.f;
    } else {
        ipu_r = 1.f; ipu_i = 0.f;
        float thp = theta[l * KK + (((u + 1) >> 1) & (KK - 1))]; // mode u+1 (wraps 511->0)
        __sincosf(thp, &ipp_i, &ipp_r);
        float thm = theta[l * KK + (u >> 1)];                    // mode u-1
        __sincosf(thm, &ipm_i, &ipm_r);
        epu_r = 1.f; epu_i = 0.f;
        float phm = phi[l * KK + (u >> 1)];
        __sincosf(phm, &epm_i, &epm_r);
    }

    const float sd_r = epp_u * ipu_r - enn_u * ipp_r - enn_um * ipm_r + epp_um * ipu_r;
    const float sd_i = epp_u * ipu_i - enn_u * ipp_i - enn_um * ipm_i + epp_um * ipu_i;
    const float d_r = 0.5f * (epu_r * sd_r - epu_i * sd_i);
    const float d_i = 0.5f * (epu_r * sd_i + epu_i * sd_r);

    const float so_r = epn_u * ipu_r + enp_u * ipp_r + enp_um * ipm_r + epn_um * ipu_r;
    const float so_i = epn_u * ipu_i + enp_u * ipp_i + enp_um * ipm_i + epn_um * ipu_i;
    const float soi_r = -so_i, soi_i = so_r;               // i * so
    const float o_r = 0.5f * (epm_r * soi_r - epm_i * soi_i);
    const float o_i = 0.5f * (epm_r * soi_i + epm_i * soi_r);

    // transposed-within-layer slot so chain's ds_read q is lane-dense:
    // slot = (u&7)*64 + (u>>3); LDS image is identity copy of this layout.
    const int slot = ((u & 7) << 6) | (u >> 3);
    coef[l * UU + slot] = make_float4(d_r, d_i, o_r, o_i);
}

// ---------------------------------------------------------------------------
// Kernel 2: chain. One wave = one batch; lane owns modes 8*lane..8*lane+7.
// Pair mix (pair p, modes 2P,2P+1):
//   y0 = c0 (x) d[2P]   + c1 (x) o[2P+1]
//   y1 = c1 (x) d[2P+1] + c0 (x) o[2P]
// even layer: c0'[p]=y1[p-1] (p=0 via shfl lane-1), c1'[p]=y0[p]
// odd  layer: c0'[p]=y1[p],  c1'[p]=y0[p+1] (p=3 via shfl lane+1)
// last layer: identity.
// ---------------------------------------------------------------------------
#define PAIR_MIX(K)                                                         \
    _Pragma("unroll")                                                       \
    for (int p = 0; p < 4; ++p) {                                           \
        const float4 ke = K[2*p], ko = K[2*p+1];                            \
        y0r[p] = c0r[p]*ke.x - c0i[p]*ke.y + c1r[p]*ko.z - c1i[p]*ko.w;     \
        y0i[p] = c0r[p]*ke.y + c0i[p]*ke.x + c1r[p]*ko.w + c1i[p]*ko.z;     \
        y1r[p] = c1r[p]*ko.x - c1i[p]*ko.y + c0r[p]*ke.z - c0i[p]*ke.w;     \
        y1i[p] = c1r[p]*ko.y + c1i[p]*ko.x + c0r[p]*ke.w + c0i[p]*ke.z;     \
    }

__global__ __launch_bounds__(64) void mesh_chain(
    const float* __restrict__ x, const float* __restrict__ gamma,
    const float4* __restrict__ coef, float* __restrict__ out)
{
    __shared__ float4 ring[RSLOTS * UU];   // 48 KB

    const int lane = threadIdx.x;          // 0..63
    const int b    = blockIdx.x;           // batch
    const int m0   = lane << 3;            // first of this lane's 8 modes

    // ---- prologue: stage layers 0..5 (48 loads in flight) ----
    #pragma unroll
    for (int pl = 0; pl < RSLOTS; ++pl) {
        STAGE(pl, pl)
    }

    // ---- init: c = x * e^{i gamma} ----
    const float4 xr0 = *(const float4*)(x + b * UU + m0);
    const float4 xr1 = *(const float4*)(x + b * UU + m0 + 4);
    const float4 xi0 = *(const float4*)(x + BB * UU + b * UU + m0);
    const float4 xi1 = *(const float4*)(x + BB * UU + b * UU + m0 + 4);
    const float xr[8] = {xr0.x, xr0.y, xr0.z, xr0.w, xr1.x, xr1.y, xr1.z, xr1.w};
    const float xi[8] = {xi0.x, xi0.y, xi0.z, xi0.w, xi1.x, xi1.y, xi1.z, xi1.w};

    float c0r[4], c0i[4], c1r[4], c1i[4];
    #pragma unroll
    for (int p = 0; p < 4; ++p) {
        float s0, cg0, s1, cg1;
        __sincosf(gamma[m0 + 2*p],     &s0, &cg0);
        __sincosf(gamma[m0 + 2*p + 1], &s1, &cg1);
        c0r[p] = xr[2*p] * cg0 - xi[2*p] * s0;
        c0i[p] = xr[2*p] * s0  + xi[2*p] * cg0;
        c1r[p] = xr[2*p+1] * cg1 - xi[2*p+1] * s1;
        c1i[p] = xr[2*p+1] * s1  + xi[2*p+1] * cg1;
    }

    const int laneM1 = (lane + 63) & 63;
    const int laneP1 = (lane + 1) & 63;

    int sa = 0;   // ring slot of the even layer this iteration (cycles 0,2,4)
    for (int it = 0; it < 256; ++it) {
        float y0r[4], y0i[4], y1r[4], y1i[4];

        // ---- even layer 2*it : carry[u] = y[u-1] ----
        WAITVM40();                     // oldest group (this layer) retired
        float4 k[8];
        #pragma unroll
        for (int q = 0; q < 8; ++q) k[q] = ring[sa * UU + q * 64 + lane];
        PAIR_MIX(k)
        {
            const float br = __shfl(y1r[3], laneM1, 64);
            const float bi = __shfl(y1i[3], laneM1, 64);
            #pragma unroll
            for (int p = 3; p > 0; --p) { c0r[p] = y1r[p-1]; c0i[p] = y1i[p-1]; }
            c0r[0] = br; c0i[0] = bi;
            #pragma unroll
            for (int p = 0; p < 4; ++p) { c1r[p] = y0r[p]; c1i[p] = y0i[p]; }
        }
        // refill the just-consumed slot with layer 2*it+6 (wraps harmlessly at tail)
        {
            const int g1 = (2 * it + RSLOTS) & (LL - 1);
            STAGE(g1, sa)
        }

        // ---- odd layer 2*it+1 ----
        WAITVM40();
        float4 n[8];
        #pragma unroll
        for (int q = 0; q < 8; ++q) n[q] = ring[(sa + 1) * UU + q * 64 + lane];
        PAIR_MIX(n)
        if (it < 255) {                 // carry[u] = y[u+1]
            const float br = __shfl(y0r[0], laneP1, 64);
            const float bi = __shfl(y0i[0], laneP1, 64);
            #pragma unroll
            for (int p = 0; p < 3; ++p) { c0r[p] = y1r[p]; c0i[p] = y1i[p];
                                          c1r[p] = y0r[p+1]; c1i[p] = y0i[p+1]; }
            c0r[3] = y1r[3]; c0i[3] = y1i[3];
            c1r[3] = br;     c1i[3] = bi;
        } else {                        // layer 511: identity perm
            #pragma unroll
            for (int p = 0; p < 4; ++p) { c0r[p] = y0r[p]; c0i[p] = y0i[p];
                                          c1r[p] = y1r[p]; c1i[p] = y1i[p]; }
        }
        {
            const int g2 = (2 * it + RSLOTS + 1) & (LL - 1);
            STAGE(g2, sa + 1)
        }

        sa += 2; if (sa >= RSLOTS) sa = 0;
    }

    // ---- store out[0][b][u] (re), out[1][b][u] (im) ----
    *(float4*)(out + b * UU + m0)               = make_float4(c0r[0], c1r[0], c0r[1], c1r[1]);
    *(float4*)(out + b * UU + m0 + 4)           = make_float4(c0r[2], c1r[2], c0r[3], c1r[3]);
    *(float4*)(out + BB * UU + b * UU + m0)     = make_float4(c0i[0], c1i[0], c0i[1], c1i[1]);
    *(float4*)(out + BB * UU + b * UU + m0 + 4) = make_float4(c0i[2], c1i[2], c0i[3], c1i[3]);
}

extern "C" void kernel_launch(void* const* d_in, const int* in_sizes, int n_in,
                              void* d_out, int out_size, void* d_ws, size_t ws_size,
                              hipStream_t stream) {
    (void)in_sizes; (void)n_in; (void)out_size; (void)ws_size;
    const float* x     = (const float*)d_in[0];
    const float* theta = (const float*)d_in[1];
    const float* phi   = (const float*)d_in[2];
    const float* gamma = (const float*)d_in[3];
    // d_in[4] = mask (all ones, folded out)
    const float* enn   = (const float*)d_in[5];
    const float* enp   = (const float*)d_in[6];
    const float* epn   = (const float*)d_in[7];
    const float* epp   = (const float*)d_in[8];
    // d_in[9] = perms, d_in[10] = pairwise_perm (fixed patterns, hardcoded)

    float4* coef = (float4*)d_ws;              // L*U*16B = 4 MB scratch
    float*  out  = (float*)d_out;

    mesh_precompute<<<LL, UU, 0, stream>>>(theta, phi, enn, enp, epn, epp, coef);
    mesh_chain<<<BB, 64, 0, stream>>>(x, gamma, coef, out);
}

// Round 5
// 192.755 us; speedup vs baseline: 2.7133x; 1.4755x over previous
//
#include <hip/hip_runtime.h>

// MeshTorchLayer: out = M_511 ... M_0 (x*e^{i gamma}); M_l = S_l A_l with
// A_l[u,u]=d[l,u], A_l[u,u^1]=o[l,u^1]; S: carry[u]=y[u-1] (l even),
// y[u+1] (l odd), identity after l=511.
// R5: fuse KF=8 layers -> 64 banded matrices G_j (width 17), fp32.
// Build scratch in LDS (15 planes), last layer converts from registers.
// Apply: 128 WGs x 512 thr (2 batches/WG, thread owns a mode PAIR),
// state as float4 pairs + halo -> dense ds_read_b128; G fp32 [j][t][pair].

#define UU 512
#define LL 512
#define BB 256
#define KK 256    // U/2
#define KF 8
#define NBK 64
#define WBAND 17

// ---------------------------------------------------------------------------
// ws layout (fused path), total 8,650,752 B:
//   [0      , 4194304)  coefT float4 [l][u]  {d.re,d.im,o.re,o.im}
//   [4194304, 8388608)  ennT/enpT/epnT/eppT float [l][u] (1 MB each)
//   [4194304, 8650752)  g32 float4 [j][t][pair]  (ALIASES eT; build runs
//                       after precompute and reads only coefT -> safe)
// ---------------------------------------------------------------------------

// ======================= transpose the four e-matrices =====================
__global__ __launch_bounds__(256) void mesh_transpose_e(
    const float* __restrict__ enn, const float* __restrict__ enp,
    const float* __restrict__ epn, const float* __restrict__ epp,
    float* __restrict__ ennT, float* __restrict__ enpT,
    float* __restrict__ epnT, float* __restrict__ eppT)
{
    __shared__ float tile[32][33];
    const float* src; float* dst;
    switch (blockIdx.z) {
        case 0:  src = enn; dst = ennT; break;
        case 1:  src = enp; dst = enpT; break;
        case 2:  src = epn; dst = epnT; break;
        default: src = epp; dst = eppT; break;
    }
    const int r0 = blockIdx.x * 32;   // u block (src rows)
    const int c0 = blockIdx.y * 32;   // l block (src cols)
    const int tx = threadIdx.x, ty = threadIdx.y;
    #pragma unroll
    for (int r = 0; r < 32; r += 8)
        tile[ty + r][tx] = src[(r0 + ty + r) * LL + c0 + tx];
    __syncthreads();
    #pragma unroll
    for (int r = 0; r < 32; r += 8)
        dst[(c0 + ty + r) * UU + r0 + tx] = tile[tx][ty + r];
}

// ========================= per-layer coef precompute =======================
// block = l, thread = u; every read/write coalesced. coefT[l][u].
__global__ __launch_bounds__(512) void mesh_precompute(
    const float* __restrict__ theta, const float* __restrict__ phi,
    const float* __restrict__ ennT,  const float* __restrict__ enpT,
    const float* __restrict__ epnT,  const float* __restrict__ eppT,
    float4* __restrict__ coefT)
{
    const int u  = threadIdx.x;
    const int l  = blockIdx.x;
    const int um = (u + UU - 1) & (UU - 1);
    const int row = l * UU;

    const float epp_u = eppT[row + u], epp_um = eppT[row + um];
    const float enn_u = ennT[row + u], enn_um = ennT[row + um];
    const float enp_u = enpT[row + u], enp_um = enpT[row + um];
    const float epn_u = epnT[row + u], epn_um = epnT[row + um];

    float ipu_r, ipu_i, ipp_r, ipp_i, ipm_r, ipm_i;
    float epu_r, epu_i, epm_r, epm_i;

    if ((u & 1) == 0) {
        const int k = u >> 1;
        float th = theta[l * KK + k];
        __sincosf(th, &ipu_i, &ipu_r);
        ipp_r = 1.f; ipp_i = 0.f;      // u+1 odd -> angle 0
        ipm_r = 1.f; ipm_i = 0.f;
        float ph = phi[l * KK + k];
        __sincosf(ph, &epu_i, &epu_r);
        epm_r = 1.f; epm_i = 0.f;
    } else {
        ipu_r = 1.f; ipu_i = 0.f;
        float thp = theta[l * KK + (((u + 1) >> 1) & (KK - 1))]; // mode u+1 (wrap)
        __sincosf(thp, &ipp_i, &ipp_r);
        float thm = theta[l * KK + (u >> 1)];                    // mode u-1
        __sincosf(thm, &ipm_i, &ipm_r);
        epu_r = 1.f; epu_i = 0.f;
        float phm = phi[l * KK + (u >> 1)];
        __sincosf(phm, &epm_i, &epm_r);
    }

    const float sd_r = epp_u * ipu_r - enn_u * ipp_r - enn_um * ipm_r + epp_um * ipu_r;
    const float sd_i = epp_u * ipu_i - enn_u * ipp_i - enn_um * ipm_i + epp_um * ipu_i;
    const float d_r = 0.5f * (epu_r * sd_r - epu_i * sd_i);
    const float d_i = 0.5f * (epu_r * sd_i + epu_i * sd_r);

    const float so_r = epn_u * ipu_r + enp_u * ipp_r + enp_um * ipm_r + epn_um * ipu_r;
    const float so_i = epn_u * ipu_i + enp_u * ipp_i + enp_um * ipm_i + epn_um * ipu_i;
    const float soi_r = -so_i, soi_i = so_r;               // i * so
    const float o_r = 0.5f * (epm_r * soi_r - epm_i * soi_i);
    const float o_i = 0.5f * (epm_r * soi_i + epm_i * soi_r);

    coefT[row + u] = make_float4(d_r, d_i, o_r, o_i);
}

// ============================ fused-band build =============================
// WG j builds G_j = M_{8j+7}...M_{8j}. Invariant after s layers: entry t of
// current-state row u is in LDS plane t at slot (u+sigma)&511 and maps to
// column u+f+t (f: 0,-2,-2,-4,... even layers subtract 2). Last layer stays
// in registers; convert writes g32[j][t][pair] with lo=-8 (j<63) / -9 (j=63).
__global__ __launch_bounds__(512) void mesh_build(
    const float4* __restrict__ coefT, float4* __restrict__ g32)
{
    __shared__ float2 gwj[15 * UU];   // 60 KB: planes 0..14
    const int u = threadIdx.x;
    const int j = blockIdx.x;

    gwj[u] = make_float2(1.f, 0.f);   // plane 0 = identity
    __syncthreads();

    int sigma = 0;
    const int tb = (u & 1) ? 0 : 2;
    float2 outr[WBAND];

    #pragma unroll
    for (int s = 0; s < KF; ++s) {
        const int W  = 2 * s + 1;       // compile-time (loop unrolled)
        const int Wn = W + 2;
        const int l  = j * KF + s;
        const int a  = (u + sigma) & (UU - 1);
        const int bx = ((u ^ 1) + sigma) & (UU - 1);
        const float4 cu = coefT[l * UU + u];         // d[l,u]
        const float4 cx = coefT[l * UU + (u ^ 1)];   // o[l,u^1]
        const float dr = cu.x, di = cu.y, orr = cx.z, oi = cx.w;

        #pragma unroll
        for (int tn = 0; tn < WBAND; ++tn) {
            float ar = 0.f, ai = 0.f;
            if (tn < Wn) {
                const int tp = tn - 1;        // row u contribution
                const int ts = tn - tb;       // row u^1 contribution
                if (0 <= tp && tp < W) {
                    float2 gv = gwj[tp * UU + a];
                    ar += dr * gv.x - di * gv.y;
                    ai += dr * gv.y + di * gv.x;
                }
                if (0 <= ts && ts < W) {
                    float2 gv = gwj[ts * UU + bx];
                    ar += orr * gv.x - oi * gv.y;
                    ai += orr * gv.y + oi * gv.x;
                }
            }
            outr[tn] = make_float2(ar, ai);
        }

        if (s < KF - 1) {
            __syncthreads();
            const int wd = (u + sigma) & (UU - 1);
            #pragma unroll
            for (int tn = 0; tn < WBAND; ++tn)
                if (tn < Wn) gwj[tn * UU + wd] = outr[tn];
            sigma += (s & 1) ? 1 : -1;
            __syncthreads();
        }
    }

    // convert from registers. j<63: layer 8j+7 shifts (+1): thread u holds
    // final row v=u-1, lo=-8. j=63: no shift: row v=u, lo=-9.
    const int v = (j == NBK - 1) ? u : ((u + UU - 1) & (UU - 1));
    float2* gb = (float2*)g32;
    #pragma unroll
    for (int t = 0; t < WBAND; ++t)
        gb[(((j * WBAND + t) << 8) + (v >> 1)) * 2 + (v & 1)] = outr[t];
}

// ================================ apply ====================================
// WG = 512 thr = 2 batches x 256 mode-pairs; grid 128. State in LDS as
// float4 pairs with 5-pair halos each side (slot = pair + 5; mode u lives
// in slot (u>>1)+5 component (u&1)). Window = 10 dense ds_read_b128.
// Row u0=2m entry t -> col u0+lo+t = w2[lo+10+t]; row u0+1 -> w2[lo+11+t].
__global__ __launch_bounds__(512) void mesh_apply(
    const float* __restrict__ x, const float* __restrict__ gamma,
    const float4* __restrict__ g32, float* __restrict__ out)
{
    __shared__ float4 cbuf[2][2][272];   // [batch][pingpong][pairslot] 17 KB
    const int tid = threadIdx.x;
    const int g   = tid >> 8;
    const int m   = tid & 255;
    const int b   = blockIdx.x * 2 + g;
    const int u0  = 2 * m;

    float s0, c0v, s1, c1v;
    __sincosf(gamma[u0],     &s0, &c0v);
    __sincosf(gamma[u0 + 1], &s1, &c1v);
    const float xr0 = x[b * UU + u0],     xi0 = x[BB * UU + b * UU + u0];
    const float xr1 = x[b * UU + u0 + 1], xi1 = x[BB * UU + b * UU + u0 + 1];
    float2 v0 = make_float2(xr0 * c0v - xi0 * s0, xr0 * s0 + xi0 * c0v);
    float2 v1 = make_float2(xr1 * c1v - xi1 * s1, xr1 * s1 + xi1 * c1v);

    #define STORE_STATE(pp)                                                   \
        do {                                                                  \
            float4 sv = make_float4(v0.x, v0.y, v1.x, v1.y);                  \
            cbuf[g][pp][m + 5] = sv;                                          \
            if (m >= 251) cbuf[g][pp][m - 251] = sv;   /* pairs 251..255 */   \
            if (m < 5)    cbuf[g][pp][m + 261] = sv;   /* pairs 0..4    */    \
        } while (0)

    STORE_STATE(0);
    __syncthreads();

    #define LOAD_STEP(jj, pp)                                                 \
        float4 gr[WBAND];                                                     \
        {                                                                     \
            const float4* gq = g32 + (jj) * (WBAND * 256) + m;                \
            _Pragma("unroll")                                                 \
            for (int t = 0; t < WBAND; ++t) gr[t] = gq[t * 256];              \
        }                                                                     \
        float4 wp[10];                                                        \
        {                                                                     \
            const float4* ws_ = &cbuf[g][pp][m];  /* pairs m-5 .. m+4 */      \
            _Pragma("unroll")                                                 \
            for (int q = 0; q < 10; ++q) wp[q] = ws_[q];                      \
        }                                                                     \
        const float2* w2 = (const float2*)wp;  /* w2[d] = col u0 + d - 10 */

    #define ACCUM(D0)                                                         \
        float a0r = 0.f, a0i = 0.f, a1r = 0.f, a1i = 0.f;                     \
        _Pragma("unroll")                                                     \
        for (int t = 0; t < WBAND; ++t) {                                     \
            const float2 wa = w2[t + (D0)];                                   \
            const float2 wb = w2[t + (D0) + 1];                               \
            a0r += gr[t].x * wa.x - gr[t].y * wa.y;                           \
            a0i += gr[t].x * wa.y + gr[t].y * wa.x;                           \
            a1r += gr[t].z * wb.x - gr[t].w * wb.y;                           \
            a1i += gr[t].z * wb.y + gr[t].w * wb.x;                           \
        }                                                                     \
        v0 = make_float2(a0r, a0i);                                           \
        v1 = make_float2(a1r, a1i);

    for (int j = 0; j < NBK - 1; ++j) {
        const int p = j & 1;
        LOAD_STEP(j, p)
        ACCUM(2)                      // lo = -8 -> d0 = 2
        STORE_STATE(1 - p);
        __syncthreads();
    }
    {   // peeled j = 63: lo = -9 -> d0 = 1; reads buffer (63&1)=1
        LOAD_STEP(NBK - 1, 1)
        ACCUM(1)
    }

    *(float2*)(out + b * UU + u0)          = make_float2(v0.x, v1.x);
    *(float2*)(out + BB * UU + b * UU + u0) = make_float2(v0.y, v1.y);
    #undef STORE_STATE
    #undef LOAD_STEP
    #undef ACCUM
}

// ===================== R3 fallback (if ws too small) =======================
#define RSLOTS 6
#define WAITVM40() __builtin_amdgcn_s_waitcnt(0x8F78)
#define STAGE(gg, ss)                                                        \
    _Pragma("unroll")                                                        \
    for (int jq = 0; jq < 8; ++jq)                                           \
        __builtin_amdgcn_global_load_lds(                                    \
            (const __attribute__((address_space(1))) void*)(coef + (gg) * UU + jq * 64 + lane), \
            (__attribute__((address_space(3))) void*)&ring[(ss) * UU + jq * 64], \
            16, 0, 0);

__global__ __launch_bounds__(512) void mesh_precompute_slot(
    const float* __restrict__ theta, const float* __restrict__ phi,
    const float* __restrict__ enn,   const float* __restrict__ enp,
    const float* __restrict__ epn,   const float* __restrict__ epp,
    float4* __restrict__ coef)
{
    const int u  = threadIdx.x;
    const int l  = blockIdx.x;
    const int um = (u + UU - 1) & (UU - 1);
    const float epp_u  = epp[u * LL + l],  epp_um = epp[um * LL + l];
    const float enn_u  = enn[u * LL + l],  enn_um = enn[um * LL + l];
    const float enp_u  = enp[u * LL + l],  enp_um = enp[um * LL + l];
    const float epn_u  = epn[u * LL + l],  epn_um = epn[um * LL + l];
    float ipu_r, ipu_i, ipp_r, ipp_i, ipm_r, ipm_i;
    float epu_r, epu_i, epm_r, epm_i;
    if ((u & 1) == 0) {
        const int k = u >> 1;
        float th = theta[l * KK + k];  __sincosf(th, &ipu_i, &ipu_r);
        ipp_r = 1.f; ipp_i = 0.f;  ipm_r = 1.f; ipm_i = 0.f;
        float phv = phi[l * KK + k];   __sincosf(phv, &epu_i, &epu_r);
        epm_r = 1.f; epm_i = 0.f;
    } else {
        ipu_r = 1.f; ipu_i = 0.f;
        float thp = theta[l * KK + (((u + 1) >> 1) & (KK - 1))]; __sincosf(thp, &ipp_i, &ipp_r);
        float thm = theta[l * KK + (u >> 1)];                    __sincosf(thm, &ipm_i, &ipm_r);
        epu_r = 1.f; epu_i = 0.f;
        float phm = phi[l * KK + (u >> 1)];                      __sincosf(phm, &epm_i, &epm_r);
    }
    const float sd_r = epp_u * ipu_r - enn_u * ipp_r - enn_um * ipm_r + epp_um * ipu_r;
    const float sd_i = epp_u * ipu_i - enn_u * ipp_i - enn_um * ipm_i + epp_um * ipu_i;
    const float d_r = 0.5f * (epu_r * sd_r - epu_i * sd_i);
    const float d_i = 0.5f * (epu_r * sd_i + epu_i * sd_r);
    const float so_r = epn_u * ipu_r + enp_u * ipp_r + enp_um * ipm_r + epn_um * ipu_r;
    const float so_i = epn_u * ipu_i + enp_u * ipp_i + enp_um * ipm_i + epn_um * ipu_i;
    const float soi_r = -so_i, soi_i = so_r;
    const float o_r = 0.5f * (epm_r * soi_r - epm_i * soi_i);
    const float o_i = 0.5f * (epm_r * soi_i + epm_i * soi_r);
    const int slot = ((u & 7) << 6) | (u >> 3);
    coef[l * UU + slot] = make_float4(d_r, d_i, o_r, o_i);
}

#define PAIR_MIX(K)                                                         \
    _Pragma("unroll")                                                       \
    for (int p = 0; p < 4; ++p) {                                           \
        const float4 ke = K[2*p], ko = K[2*p+1];                            \
        y0r[p] = c0r[p]*ke.x - c0i[p]*ke.y + c1r[p]*ko.z - c1i[p]*ko.w;     \
        y0i[p] = c0r[p]*ke.y + c0i[p]*ke.x + c1r[p]*ko.w + c1i[p]*ko.z;     \
        y1r[p] = c1r[p]*ko.x - c1i[p]*ko.y + c0r[p]*ke.z - c0i[p]*ke.w;     \
        y1i[p] = c1r[p]*ko.y + c1i[p]*ko.x + c0r[p]*ke.w + c0i[p]*ke.z;     \
    }

__global__ __launch_bounds__(64) void mesh_chain_r3(
    const float* __restrict__ x, const float* __restrict__ gamma,
    const float4* __restrict__ coef, float* __restrict__ out)
{
    __shared__ float4 ring[RSLOTS * UU];
    const int lane = threadIdx.x;
    const int b    = blockIdx.x;
    const int m0   = lane << 3;
    #pragma unroll
    for (int pl = 0; pl < RSLOTS; ++pl) { STAGE(pl, pl) }
    const float4 xr0 = *(const float4*)(x + b * UU + m0);
    const float4 xr1 = *(const float4*)(x + b * UU + m0 + 4);
    const float4 xi0 = *(const float4*)(x + BB * UU + b * UU + m0);
    const float4 xi1 = *(const float4*)(x + BB * UU + b * UU + m0 + 4);
    const float xr[8] = {xr0.x, xr0.y, xr0.z, xr0.w, xr1.x, xr1.y, xr1.z, xr1.w};
    const float xi[8] = {xi0.x, xi0.y, xi0.z, xi0.w, xi1.x, xi1.y, xi1.z, xi1.w};
    float c0r[4], c0i[4], c1r[4], c1i[4];
    #pragma unroll
    for (int p = 0; p < 4; ++p) {
        float s0, cg0, s1, cg1;
        __sincosf(gamma[m0 + 2*p],     &s0, &cg0);
        __sincosf(gamma[m0 + 2*p + 1], &s1, &cg1);
        c0r[p] = xr[2*p] * cg0 - xi[2*p] * s0;
        c0i[p] = xr[2*p] * s0  + xi[2*p] * cg0;
        c1r[p] = xr[2*p+1] * cg1 - xi[2*p+1] * s1;
        c1i[p] = xr[2*p+1] * s1  + xi[2*p+1] * cg1;
    }
    const int laneM1 = (lane + 63) & 63;
    const int laneP1 = (lane + 1) & 63;
    int sa = 0;
    for (int it = 0; it < 256; ++it) {
        float y0r[4], y0i[4], y1r[4], y1i[4];
        WAITVM40();
        float4 k[8];
        #pragma unroll
        for (int q = 0; q < 8; ++q) k[q] = ring[sa * UU + q * 64 + lane];
        PAIR_MIX(k)
        {
            const float br = __shfl(y1r[3], laneM1, 64);
            const float bi = __shfl(y1i[3], laneM1, 64);
            #pragma unroll
            for (int p = 3; p > 0; --p) { c0r[p] = y1r[p-1]; c0i[p] = y1i[p-1]; }
            c0r[0] = br; c0i[0] = bi;
            #pragma unroll
            for (int p = 0; p < 4; ++p) { c1r[p] = y0r[p]; c1i[p] = y0i[p]; }
        }
        { const int g1 = (2 * it + RSLOTS) & (LL - 1); STAGE(g1, sa) }
        WAITVM40();
        float4 n[8];
        #pragma unroll
        for (int q = 0; q < 8; ++q) n[q] = ring[(sa + 1) * UU + q * 64 + lane];
        PAIR_MIX(n)
        if (it < 255) {
            const float br = __shfl(y0r[0], laneP1, 64);
            const float bi = __shfl(y0i[0], laneP1, 64);
            #pragma unroll
            for (int p = 0; p < 3; ++p) { c0r[p] = y1r[p]; c0i[p] = y1i[p];
                                          c1r[p] = y0r[p+1]; c1i[p] = y0i[p+1]; }
            c0r[3] = y1r[3]; c0i[3] = y1i[3];
            c1r[3] = br;     c1i[3] = bi;
        } else {
            #pragma unroll
            for (int p = 0; p < 4; ++p) { c0r[p] = y0r[p]; c0i[p] = y0i[p];
                                          c1r[p] = y1r[p]; c1i[p] = y1i[p]; }
        }
        { const int g2 = (2 * it + RSLOTS + 1) & (LL - 1); STAGE(g2, sa + 1) }
        sa += 2; if (sa >= RSLOTS) sa = 0;
    }
    *(float4*)(out + b * UU + m0)               = make_float4(c0r[0], c1r[0], c0r[1], c1r[1]);
    *(float4*)(out + b * UU + m0 + 4)           = make_float4(c0r[2], c1r[2], c0r[3], c1r[3]);
    *(float4*)(out + BB * UU + b * UU + m0)     = make_float4(c0i[0], c1i[0], c0i[1], c1i[1]);
    *(float4*)(out + BB * UU + b * UU + m0 + 4) = make_float4(c0i[2], c1i[2], c0i[3], c1i[3]);
}

// ================================ launch ===================================
extern "C" void kernel_launch(void* const* d_in, const int* in_sizes, int n_in,
                              void* d_out, int out_size, void* d_ws, size_t ws_size,
                              hipStream_t stream) {
    (void)in_sizes; (void)n_in; (void)out_size;
    const float* x     = (const float*)d_in[0];
    const float* theta = (const float*)d_in[1];
    const float* phi   = (const float*)d_in[2];
    const float* gamma = (const float*)d_in[3];
    // d_in[4] = mask (all ones, folded out)
    const float* enn   = (const float*)d_in[5];
    const float* enp   = (const float*)d_in[6];
    const float* epn   = (const float*)d_in[7];
    const float* epp   = (const float*)d_in[8];
    // d_in[9] = perms, d_in[10] = pairwise_perm (fixed patterns, hardcoded)
    float* out = (float*)d_out;

    if (ws_size >= (size_t)8650752) {
        float4* coefT = (float4*)d_ws;                          // [0, 4 MB)
        float*  ennT  = (float*)((char*)d_ws + 4194304);
        float*  enpT  = (float*)((char*)d_ws + 5242880);
        float*  epnT  = (float*)((char*)d_ws + 6291456);
        float*  eppT  = (float*)((char*)d_ws + 7340032);
        float4* g32   = (float4*)((char*)d_ws + 4194304);       // aliases eT

        mesh_transpose_e<<<dim3(16, 16, 4), dim3(32, 8), 0, stream>>>(
            enn, enp, epn, epp, ennT, enpT, epnT, eppT);
        mesh_precompute<<<LL, UU, 0, stream>>>(theta, phi, ennT, enpT, epnT, eppT, coefT);
        mesh_build<<<NBK, UU, 0, stream>>>(coefT, g32);
        mesh_apply<<<BB / 2, UU, 0, stream>>>(x, gamma, g32, out);
    } else {
        // fallback: R3 register-chain path (needs 4 MB ws)
        float4* coef = (float4*)d_ws;
        mesh_precompute_slot<<<LL, UU, 0, stream>>>(theta, phi, enn, enp, epn, epp, coef);
        mesh_chain_r3<<<BB, 64, 0, stream>>>(x, gamma, coef, out);
    }
}

// Round 6
// 192.310 us; speedup vs baseline: 2.7196x; 1.0023x over previous
//
#include <hip/hip_runtime.h>

// MeshTorchLayer: out = M_511 ... M_0 (x*e^{i gamma}); M_l = S_l A_l.
// R6: build 64 width-17 band matrices (proven R5), NEW: merge pairs into
// 32 width-33 bands (halves serial steps), apply with 32 steps x 33 taps.

#define UU 512
#define LL 512
#define BB 256
#define KK 256    // U/2
#define KF 8
#define NBK 64
#define WBAND 17
#define NBK2 32
#define WB2 33

// ---------------------------------------------------------------------------
// ws layout (fused path), total 12,976,128 B:
//   [0       , 4194304 )  coefT float4 [l][u]
//   [4194304 , 8388608 )  ennT/enpT/epnT/eppT float [l][u] (1 MB each)
//   [4194304 , 8650752 )  g32 float4 [j][t][pair] (ALIASES eT; build runs
//                         after precompute, reads only coefT -> safe)
//   [8650752 ,12976128 )  g2  float4 [q][t][pair] merged width-33 bands
// ---------------------------------------------------------------------------

// ======================= transpose the four e-matrices =====================
__global__ __launch_bounds__(256) void mesh_transpose_e(
    const float* __restrict__ enn, const float* __restrict__ enp,
    const float* __restrict__ epn, const float* __restrict__ epp,
    float* __restrict__ ennT, float* __restrict__ enpT,
    float* __restrict__ epnT, float* __restrict__ eppT)
{
    __shared__ float tile[32][33];
    const float* src; float* dst;
    switch (blockIdx.z) {
        case 0:  src = enn; dst = ennT; break;
        case 1:  src = enp; dst = enpT; break;
        case 2:  src = epn; dst = epnT; break;
        default: src = epp; dst = eppT; break;
    }
    const int r0 = blockIdx.x * 32;
    const int c0 = blockIdx.y * 32;
    const int tx = threadIdx.x, ty = threadIdx.y;
    #pragma unroll
    for (int r = 0; r < 32; r += 8)
        tile[ty + r][tx] = src[(r0 + ty + r) * LL + c0 + tx];
    __syncthreads();
    #pragma unroll
    for (int r = 0; r < 32; r += 8)
        dst[(c0 + ty + r) * UU + r0 + tx] = tile[tx][ty + r];
}

// ========================= per-layer coef precompute =======================
__global__ __launch_bounds__(512) void mesh_precompute(
    const float* __restrict__ theta, const float* __restrict__ phi,
    const float* __restrict__ ennT,  const float* __restrict__ enpT,
    const float* __restrict__ epnT,  const float* __restrict__ eppT,
    float4* __restrict__ coefT)
{
    const int u  = threadIdx.x;
    const int l  = blockIdx.x;
    const int um = (u + UU - 1) & (UU - 1);
    const int row = l * UU;

    const float epp_u = eppT[row + u], epp_um = eppT[row + um];
    const float enn_u = ennT[row + u], enn_um = ennT[row + um];
    const float enp_u = enpT[row + u], enp_um = enpT[row + um];
    const float epn_u = epnT[row + u], epn_um = epnT[row + um];

    float ipu_r, ipu_i, ipp_r, ipp_i, ipm_r, ipm_i;
    float epu_r, epu_i, epm_r, epm_i;

    if ((u & 1) == 0) {
        const int k = u >> 1;
        float th = theta[l * KK + k];
        __sincosf(th, &ipu_i, &ipu_r);
        ipp_r = 1.f; ipp_i = 0.f;
        ipm_r = 1.f; ipm_i = 0.f;
        float ph = phi[l * KK + k];
        __sincosf(ph, &epu_i, &epu_r);
        epm_r = 1.f; epm_i = 0.f;
    } else {
        ipu_r = 1.f; ipu_i = 0.f;
        float thp = theta[l * KK + (((u + 1) >> 1) & (KK - 1))];
        __sincosf(thp, &ipp_i, &ipp_r);
        float thm = theta[l * KK + (u >> 1)];
        __sincosf(thm, &ipm_i, &ipm_r);
        epu_r = 1.f; epu_i = 0.f;
        float phm = phi[l * KK + (u >> 1)];
        __sincosf(phm, &epm_i, &epm_r);
    }

    const float sd_r = epp_u * ipu_r - enn_u * ipp_r - enn_um * ipm_r + epp_um * ipu_r;
    const float sd_i = epp_u * ipu_i - enn_u * ipp_i - enn_um * ipm_i + epp_um * ipu_i;
    const float d_r = 0.5f * (epu_r * sd_r - epu_i * sd_i);
    const float d_i = 0.5f * (epu_r * sd_i + epu_i * sd_r);

    const float so_r = epn_u * ipu_r + enp_u * ipp_r + enp_um * ipm_r + epn_um * ipu_r;
    const float so_i = epn_u * ipu_i + enp_u * ipp_i + enp_um * ipm_i + epn_um * ipu_i;
    const float soi_r = -so_i, soi_i = so_r;
    const float o_r = 0.5f * (epm_r * soi_r - epm_i * soi_i);
    const float o_i = 0.5f * (epm_r * soi_i + epm_i * soi_r);

    coefT[row + u] = make_float4(d_r, d_i, o_r, o_i);
}

// ============================ fused-band build =============================
// (unchanged from R5, verified) g32[j][t][pair] fp32; row u entry t -> col
// u + lo_j + t, lo_j = -8 (j<63) / -9 (j=63).
__global__ __launch_bounds__(512) void mesh_build(
    const float4* __restrict__ coefT, float4* __restrict__ g32)
{
    __shared__ float2 gwj[15 * UU];
    const int u = threadIdx.x;
    const int j = blockIdx.x;

    gwj[u] = make_float2(1.f, 0.f);
    __syncthreads();

    int sigma = 0;
    const int tb = (u & 1) ? 0 : 2;
    float2 outr[WBAND];

    #pragma unroll
    for (int s = 0; s < KF; ++s) {
        const int W  = 2 * s + 1;
        const int Wn = W + 2;
        const int l  = j * KF + s;
        const int a  = (u + sigma) & (UU - 1);
        const int bx = ((u ^ 1) + sigma) & (UU - 1);
        const float4 cu = coefT[l * UU + u];
        const float4 cx = coefT[l * UU + (u ^ 1)];
        const float dr = cu.x, di = cu.y, orr = cx.z, oi = cx.w;

        #pragma unroll
        for (int tn = 0; tn < WBAND; ++tn) {
            float ar = 0.f, ai = 0.f;
            if (tn < Wn) {
                const int tp = tn - 1;
                const int ts = tn - tb;
                if (0 <= tp && tp < W) {
                    float2 gv = gwj[tp * UU + a];
                    ar += dr * gv.x - di * gv.y;
                    ai += dr * gv.y + di * gv.x;
                }
                if (0 <= ts && ts < W) {
                    float2 gv = gwj[ts * UU + bx];
                    ar += orr * gv.x - oi * gv.y;
                    ai += orr * gv.y + oi * gv.x;
                }
            }
            outr[tn] = make_float2(ar, ai);
        }

        if (s < KF - 1) {
            __syncthreads();
            const int wd = (u + sigma) & (UU - 1);
            #pragma unroll
            for (int tn = 0; tn < WBAND; ++tn)
                if (tn < Wn) gwj[tn * UU + wd] = outr[tn];
            sigma += (s & 1) ? 1 : -1;
            __syncthreads();
        }
    }

    const int v = (j == NBK - 1) ? u : ((u + UU - 1) & (UU - 1));
    float2* gb = (float2*)g32;
    #pragma unroll
    for (int t = 0; t < WBAND; ++t)
        gb[(((j * WBAND + t) << 8) + (v >> 1)) * 2 + (v & 1)] = outr[t];
}

// ================================ merge ====================================
// G'_q = G_{2q+1} * G_{2q}: width 17 o 17 -> 33, lo' = loA + loB.
// G'[u][ta+tb] += A[u][ta] (x) B[(u+loA+ta)&511][tb].
// grid (32,2), block 256: u = by*256+tid. All global reads/writes coalesced.
__global__ __launch_bounds__(256) void mesh_merge(
    const float4* __restrict__ g32, float4* __restrict__ g2)
{
    const int q  = blockIdx.x;
    const int u  = blockIdx.y * 256 + threadIdx.x;
    const int jA = 2 * q + 1, jB = 2 * q;
    const int loA = (jA == NBK - 1) ? -9 : -8;

    const float2* gb = (const float2*)g32;

    float2 a[WBAND];
    #pragma unroll
    for (int ta = 0; ta < WBAND; ++ta)
        a[ta] = gb[(((jA * WBAND + ta) << 8) + (u >> 1)) * 2 + (u & 1)];

    float2 outv[WB2];
    #pragma unroll
    for (int t = 0; t < WB2; ++t) outv[t] = make_float2(0.f, 0.f);

    #pragma unroll
    for (int ta = 0; ta < WBAND; ++ta) {
        const int k = (u + loA + ta + UU) & (UU - 1);
        float2 brow[WBAND];
        #pragma unroll
        for (int tbq = 0; tbq < WBAND; ++tbq)
            brow[tbq] = gb[(((jB * WBAND + tbq) << 8) + (k >> 1)) * 2 + (k & 1)];
        #pragma unroll
        for (int tbq = 0; tbq < WBAND; ++tbq) {
            outv[ta + tbq].x += a[ta].x * brow[tbq].x - a[ta].y * brow[tbq].y;
            outv[ta + tbq].y += a[ta].x * brow[tbq].y + a[ta].y * brow[tbq].x;
        }
    }

    float2* g2b = (float2*)g2;
    #pragma unroll
    for (int t = 0; t < WB2; ++t)
        g2b[(((q * WB2 + t) << 8) + (u >> 1)) * 2 + (u & 1)] = outv[t];
}

// ================================ apply ====================================
// 32 steps x width 33. WG = 512 thr = 2 batches x 256 pairs; grid 128.
// lo = -16 (q<31) / -17 (q=31). Window = 19 pairs (halo 9), w2[d] = mode
// u0-18+d. Row u0 entry t -> d = t + lo + 18; row u0+1 -> +1.
__global__ __launch_bounds__(512, 2) void mesh_apply(
    const float* __restrict__ x, const float* __restrict__ gamma,
    const float4* __restrict__ g2, float* __restrict__ out)
{
    __shared__ float4 cbuf[2][2][274];
    const int tid = threadIdx.x;
    const int g   = tid >> 8;
    const int m   = tid & 255;
    const int b   = blockIdx.x * 2 + g;
    const int u0  = 2 * m;

    float s0, c0v, s1, c1v;
    __sincosf(gamma[u0],     &s0, &c0v);
    __sincosf(gamma[u0 + 1], &s1, &c1v);
    const float xr0 = x[b * UU + u0],     xi0 = x[BB * UU + b * UU + u0];
    const float xr1 = x[b * UU + u0 + 1], xi1 = x[BB * UU + b * UU + u0 + 1];
    float2 v0 = make_float2(xr0 * c0v - xi0 * s0, xr0 * s0 + xi0 * c0v);
    float2 v1 = make_float2(xr1 * c1v - xi1 * s1, xr1 * s1 + xi1 * c1v);

    #define STORE_STATE(pp)                                                   \
        do {                                                                  \
            float4 sv = make_float4(v0.x, v0.y, v1.x, v1.y);                  \
            cbuf[g][pp][m + 9] = sv;                                          \
            if (m >= 247) cbuf[g][pp][m - 247] = sv;                          \
            if (m < 9)    cbuf[g][pp][m + 265] = sv;                          \
        } while (0)

    STORE_STATE(0);
    __syncthreads();

    // per-step: window regs (19 float4) + two 17-reg G half-loads.
    #define APPLY_STEP(jj, pp, D0)                                           \
        do {                                                                  \
            float4 wp[19];                                                    \
            {                                                                 \
                const float4* ws_ = &cbuf[g][pp][m];                          \
                _Pragma("unroll")                                             \
                for (int qq = 0; qq < 19; ++qq) wp[qq] = ws_[qq];             \
            }                                                                 \
            const float2* w2 = (const float2*)wp;                             \
            const float4* gq = g2 + (jj) * (WB2 * 256) + m;                   \
            float a0r = 0.f, a0i = 0.f, a1r = 0.f, a1i = 0.f;                 \
            {                                                                 \
                float4 gr[17];                                                \
                _Pragma("unroll")                                             \
                for (int t = 0; t < 17; ++t) gr[t] = gq[t * 256];             \
                _Pragma("unroll")                                             \
                for (int t = 0; t < 17; ++t) {                                \
                    const float2 wa = w2[t + (D0)];                           \
                    const float2 wb = w2[t + (D0) + 1];                       \
                    a0r += gr[t].x * wa.x - gr[t].y * wa.y;                   \
                    a0i += gr[t].x * wa.y + gr[t].y * wa.x;                   \
                    a1r += gr[t].z * wb.x - gr[t].w * wb.y;                   \
                    a1i += gr[t].z * wb.y + gr[t].w * wb.x;                   \
                }                                                             \
            }                                                                 \
            {                                                                 \
                float4 gr[16];                                                \
                _Pragma("unroll")                                             \
                for (int t = 0; t < 16; ++t) gr[t] = gq[(17 + t) * 256];      \
                _Pragma("unroll")                                             \
                for (int t = 0; t < 16; ++t) {                                \
                    const float2 wa = w2[17 + t + (D0)];                      \
                    const float2 wb = w2[17 + t + (D0) + 1];                  \
                    a0r += gr[t].x * wa.x - gr[t].y * wa.y;                   \
                    a0i += gr[t].x * wa.y + gr[t].y * wa.x;                   \
                    a1r += gr[t].z * wb.x - gr[t].w * wb.y;                   \
                    a1i += gr[t].z * wb.y + gr[t].w * wb.x;                   \
                }                                                             \
            }                                                                 \
            v0 = make_float2(a0r, a0i);                                       \
            v1 = make_float2(a1r, a1i);                                       \
        } while (0)

    for (int j = 0; j < NBK2 - 1; ++j) {
        const int p = j & 1;
        APPLY_STEP(j, p, 2);          // lo = -16 -> d0 = 2
        STORE_STATE(1 - p);
        __syncthreads();
    }
    APPLY_STEP(NBK2 - 1, 1, 1);       // q = 31: lo = -17 -> d0 = 1

    *(float2*)(out + b * UU + u0)           = make_float2(v0.x, v1.x);
    *(float2*)(out + BB * UU + b * UU + u0) = make_float2(v0.y, v1.y);
    #undef STORE_STATE
    #undef APPLY_STEP
}

// ===================== R3 fallback (if ws too small) =======================
#define RSLOTS 6
#define WAITVM40() __builtin_amdgcn_s_waitcnt(0x8F78)
#define STAGE(gg, ss)                                                        \
    _Pragma("unroll")                                                        \
    for (int jq = 0; jq < 8; ++jq)                                           \
        __builtin_amdgcn_global_load_lds(                                    \
            (const __attribute__((address_space(1))) void*)(coef + (gg) * UU + jq * 64 + lane), \
            (__attribute__((address_space(3))) void*)&ring[(ss) * UU + jq * 64], \
            16, 0, 0);

__global__ __launch_bounds__(512) void mesh_precompute_slot(
    const float* __restrict__ theta, const float* __restrict__ phi,
    const float* __restrict__ enn,   const float* __restrict__ enp,
    const float* __restrict__ epn,   const float* __restrict__ epp,
    float4* __restrict__ coef)
{
    const int u  = threadIdx.x;
    const int l  = blockIdx.x;
    const int um = (u + UU - 1) & (UU - 1);
    const float epp_u  = epp[u * LL + l],  epp_um = epp[um * LL + l];
    const float enn_u  = enn[u * LL + l],  enn_um = enn[um * LL + l];
    const float enp_u  = enp[u * LL + l],  enp_um = enp[um * LL + l];
    const float epn_u  = epn[u * LL + l],  epn_um = epn[um * LL + l];
    float ipu_r, ipu_i, ipp_r, ipp_i, ipm_r, ipm_i;
    float epu_r, epu_i, epm_r, epm_i;
    if ((u & 1) == 0) {
        const int k = u >> 1;
        float th = theta[l * KK + k];  __sincosf(th, &ipu_i, &ipu_r);
        ipp_r = 1.f; ipp_i = 0.f;  ipm_r = 1.f; ipm_i = 0.f;
        float phv = phi[l * KK + k];   __sincosf(phv, &epu_i, &epu_r);
        epm_r = 1.f; epm_i = 0.f;
    } else {
        ipu_r = 1.f; ipu_i = 0.f;
        float thp = theta[l * KK + (((u + 1) >> 1) & (KK - 1))]; __sincosf(thp, &ipp_i, &ipp_r);
        float thm = theta[l * KK + (u >> 1)];                    __sincosf(thm, &ipm_i, &ipm_r);
        epu_r = 1.f; epu_i = 0.f;
        float phm = phi[l * KK + (u >> 1)];                      __sincosf(phm, &epm_i, &epm_r);
    }
    const float sd_r = epp_u * ipu_r - enn_u * ipp_r - enn_um * ipm_r + epp_um * ipu_r;
    const float sd_i = epp_u * ipu_i - enn_u * ipp_i - enn_um * ipm_i + epp_um * ipu_i;
    const float d_r = 0.5f * (epu_r * sd_r - epu_i * sd_i);
    const float d_i = 0.5f * (epu_r * sd_i + epu_i * sd_r);
    const float so_r = epn_u * ipu_r + enp_u * ipp_r + enp_um * ipm_r + epn_um * ipu_r;
    const float so_i = epn_u * ipu_i + enp_u * ipp_i + enp_um * ipm_i + epn_um * ipu_i;
    const float soi_r = -so_i, soi_i = so_r;
    const float o_r = 0.5f * (epm_r * soi_r - epm_i * soi_i);
    const float o_i = 0.5f * (epm_r * soi_i + epm_i * soi_r);
    const int slot = ((u & 7) << 6) | (u >> 3);
    coef[l * UU + slot] = make_float4(d_r, d_i, o_r, o_i);
}

#define PAIR_MIX(K)                                                         \
    _Pragma("unroll")                                                       \
    for (int p = 0; p < 4; ++p) {                                           \
        const float4 ke = K[2*p], ko = K[2*p+1];                            \
        y0r[p] = c0r[p]*ke.x - c0i[p]*ke.y + c1r[p]*ko.z - c1i[p]*ko.w;     \
        y0i[p] = c0r[p]*ke.y + c0i[p]*ke.x + c1r[p]*ko.w + c1i[p]*ko.z;     \
        y1r[p] = c1r[p]*ko.x - c1i[p]*ko.y + c0r[p]*ke.z - c0i[p]*ke.w;     \
        y1i[p] = c1r[p]*ko.y + c1i[p]*ko.x + c0r[p]*ke.w + c0i[p]*ke.z;     \
    }

__global__ __launch_bounds__(64) void mesh_chain_r3(
    const float* __restrict__ x, const float* __restrict__ gamma,
    const float4* __restrict__ coef, float* __restrict__ out)
{
    __shared__ float4 ring[RSLOTS * UU];
    const int lane = threadIdx.x;
    const int b    = blockIdx.x;
    const int m0   = lane << 3;
    #pragma unroll
    for (int pl = 0; pl < RSLOTS; ++pl) { STAGE(pl, pl) }
    const float4 xr0 = *(const float4*)(x + b * UU + m0);
    const float4 xr1 = *(const float4*)(x + b * UU + m0 + 4);
    const float4 xi0 = *(const float4*)(x + BB * UU + b * UU + m0);
    const float4 xi1 = *(const float4*)(x + BB * UU + b * UU + m0 + 4);
    const float xr[8] = {xr0.x, xr0.y, xr0.z, xr0.w, xr1.x, xr1.y, xr1.z, xr1.w};
    const float xi[8] = {xi0.x, xi0.y, xi0.z, xi0.w, xi1.x, xi1.y, xi1.z, xi1.w};
    float c0r[4], c0i[4], c1r[4], c1i[4];
    #pragma unroll
    for (int p = 0; p < 4; ++p) {
        float s0, cg0, s1, cg1;
        __sincosf(gamma[m0 + 2*p],     &s0, &cg0);
        __sincosf(gamma[m0 + 2*p + 1], &s1, &cg1);
        c0r[p] = xr[2*p] * cg0 - xi[2*p] * s0;
        c0i[p] = xr[2*p] * s0  + xi[2*p] * cg0;
        c1r[p] = xr[2*p+1] * cg1 - xi[2*p+1] * s1;
        c1i[p] = xr[2*p+1] * s1  + xi[2*p+1] * cg1;
    }
    const int laneM1 = (lane + 63) & 63;
    const int laneP1 = (lane + 1) & 63;
    int sa = 0;
    for (int it = 0; it < 256; ++it) {
        float y0r[4], y0i[4], y1r[4], y1i[4];
        WAITVM40();
        float4 k[8];
        #pragma unroll
        for (int q = 0; q < 8; ++q) k[q] = ring[sa * UU + q * 64 + lane];
        PAIR_MIX(k)
        {
            const float br = __shfl(y1r[3], laneM1, 64);
            const float bi = __shfl(y1i[3], laneM1, 64);
            #pragma unroll
            for (int p = 3; p > 0; --p) { c0r[p] = y1r[p-1]; c0i[p] = y1i[p-1]; }
            c0r[0] = br; c0i[0] = bi;
            #pragma unroll
            for (int p = 0; p < 4; ++p) { c1r[p] = y0r[p]; c1i[p] = y0i[p]; }
        }
        { const int g1 = (2 * it + RSLOTS) & (LL - 1); STAGE(g1, sa) }
        WAITVM40();
        float4 n[8];
        #pragma unroll
        for (int q = 0; q < 8; ++q) n[q] = ring[(sa + 1) * UU + q * 64 + lane];
        PAIR_MIX(n)
        if (it < 255) {
            const float br = __shfl(y0r[0], laneP1, 64);
            const float bi = __shfl(y0i[0], laneP1, 64);
            #pragma unroll
            for (int p = 0; p < 3; ++p) { c0r[p] = y1r[p]; c0i[p] = y1i[p];
                                          c1r[p] = y0r[p+1]; c1i[p] = y0i[p+1]; }
            c0r[3] = y1r[3]; c0i[3] = y1i[3];
            c1r[3] = br;     c1i[3] = bi;
        } else {
            #pragma unroll
            for (int p = 0; p < 4; ++p) { c0r[p] = y0r[p]; c0i[p] = y0i[p];
                                          c1r[p] = y1r[p]; c1i[p] = y1i[p]; }
        }
        { const int g2 = (2 * it + RSLOTS + 1) & (LL - 1); STAGE(g2, sa + 1) }
        sa += 2; if (sa >= RSLOTS) sa = 0;
    }
    *(float4*)(out + b * UU + m0)               = make_float4(c0r[0], c1r[0], c0r[1], c1r[1]);
    *(float4*)(out + b * UU + m0 + 4)           = make_float4(c0r[2], c1r[2], c0r[3], c1r[3]);
    *(float4*)(out + BB * UU + b * UU + m0)     = make_float4(c0i[0], c1i[0], c0i[1], c1i[1]);
    *(float4*)(out + BB * UU + b * UU + m0 + 4) = make_float4(c0i[2], c1i[2], c0i[3], c1i[3]);
}

// ================================ launch ===================================
extern "C" void kernel_launch(void* const* d_in, const int* in_sizes, int n_in,
                              void* d_out, int out_size, void* d_ws, size_t ws_size,
                              hipStream_t stream) {
    (void)in_sizes; (void)n_in; (void)out_size;
    const float* x     = (const float*)d_in[0];
    const float* theta = (const float*)d_in[1];
    const float* phi   = (const float*)d_in[2];
    const float* gamma = (const float*)d_in[3];
    // d_in[4] = mask (all ones, folded out)
    const float* enn   = (const float*)d_in[5];
    const float* enp   = (const float*)d_in[6];
    const float* epn   = (const float*)d_in[7];
    const float* epp   = (const float*)d_in[8];
    // d_in[9] = perms, d_in[10] = pairwise_perm (fixed patterns, hardcoded)
    float* out = (float*)d_out;

    if (ws_size >= (size_t)12976128) {
        float4* coefT = (float4*)d_ws;                          // [0, 4 MB)
        float*  ennT  = (float*)((char*)d_ws + 4194304);
        float*  enpT  = (float*)((char*)d_ws + 5242880);
        float*  epnT  = (float*)((char*)d_ws + 6291456);
        float*  eppT  = (float*)((char*)d_ws + 7340032);
        float4* g32   = (float4*)((char*)d_ws + 4194304);       // aliases eT
        float4* g2    = (float4*)((char*)d_ws + 8650752);

        mesh_transpose_e<<<dim3(16, 16, 4), dim3(32, 8), 0, stream>>>(
            enn, enp, epn, epp, ennT, enpT, epnT, eppT);
        mesh_precompute<<<LL, UU, 0, stream>>>(theta, phi, ennT, enpT, epnT, eppT, coefT);
        mesh_build<<<NBK, UU, 0, stream>>>(coefT, g32);
        mesh_merge<<<dim3(NBK2, 2), 256, 0, stream>>>(g32, g2);
        mesh_apply<<<BB / 2, UU, 0, stream>>>(x, gamma, g2, out);
    } else {
        // fallback: R3 register-chain path (needs 4 MB ws)
        float4* coef = (float4*)d_ws;
        mesh_precompute_slot<<<LL, UU, 0, stream>>>(theta, phi, enn, enp, epn, epp, coef);
        mesh_chain_r3<<<BB, 64, 0, stream>>>(x, gamma, coef, out);
    }
}